// Round 3
// baseline (630.621 us; speedup 1.0000x reference)
//
#include <hip/hip_runtime.h>
#include <stdint.h>

typedef _Float16 f16;
typedef __attribute__((ext_vector_type(8))) _Float16 f16x8;
typedef __attribute__((ext_vector_type(4))) float f32x4;

#define NN 4096
#define UN 256

__device__ __forceinline__ f16x8 ld_f16x8(const f16* p){ return *(const f16x8*)p; }
__device__ __forceinline__ f32x4 zero4(){ f32x4 z = {0.f,0.f,0.f,0.f}; return z; }

// ---------------- K0: wgT[u][node] = (f16) w_gcn^T ----------------
// wg: [4096 nodes][256 units] f32 -> wgT: [256][4096] f16
__global__ __launch_bounds__(256) void k0_wgT(
    const float* __restrict__ wg, f16* __restrict__ wgT)
{
  __shared__ float tile[32][33];
  const int b = blockIdx.x;              // 1024 = 128 node-tiles x 8 unit-tiles
  const int tr = b >> 3, tc = b & 7;
  const int tx = threadIdx.x & 31, ty = threadIdx.x >> 5;
  const int r0 = tr * 32, c0 = tc * 32;  // r0: node, c0: unit
  #pragma unroll
  for (int i = 0; i < 4; i++){
    int r = ty + i*8;
    tile[r][tx] = wg[(size_t)(r0 + r) * UN + c0 + tx];
  }
  __syncthreads();
  #pragma unroll
  for (int i = 0; i < 4; i++){
    int r = ty + i*8;
    wgT[(size_t)(c0 + r) * NN + r0 + tx] = (f16)tile[tx][r];
  }
}

// ---------------- K1: W2T[u][node] += (sum_g wa_g adj_g) @ w_gcn --
// A = adj_mix (f32, split into f16 hi+lo), B = wgT (f16). f32 atomic out.
// Block: 32 (m=node) x 256 (n=unit) tile; K split 4-way across grid.y.
#define LD1 72   // f16 leading dim; 144 B row stride (16B-aligned)

union K1S {
  struct { f16 Ah[32*LD1]; f16 Al[32*LD1]; f16 B[256*LD1]; } s;  // 46080 B
  float T[32*257];                                                // 32896 B
};

__global__ __launch_bounds__(256) void k1_w2t(
    const float* __restrict__ adj, const float* __restrict__ wa,
    const f16* __restrict__ wgT, float* __restrict__ W2T)
{
  __shared__ K1S sm;
  const int t = threadIdx.x;
  const int mbase = blockIdx.x * 32;
  const int kbase = blockIdx.y * 1024;
  const float wa0 = wa[0], wa1 = wa[1], wa2 = wa[2];
  const int lane = t & 63, wv = t >> 6;
  const int mh = wv & 1, nh = wv >> 1;    // m-half (16 rows), n-half (128 cols)
  const int qm = lane & 15, quad = lane >> 4;

  f32x4 acc[8] = { zero4(), zero4(), zero4(), zero4(),
                   zero4(), zero4(), zero4(), zero4() };

  const int ar = t >> 3;          // 0..31 : A row
  const int kc = (t & 7) * 8;     // 0..56 : k chunk of 8 f32
  const size_t gs = (size_t)NN * NN;
  const float* pa = adj + (size_t)(mbase + ar) * NN + kbase + kc;

  for (int kt = 0; kt < 1024; kt += 64){
    // --- A: 3 graphs x 8 f32 ---
    f32x4 g[3][2];
    #pragma unroll
    for (int g3 = 0; g3 < 3; g3++)
      #pragma unroll
      for (int h2 = 0; h2 < 2; h2++)
        g[g3][h2] = *(const f32x4*)(pa + kt + (size_t)g3*gs + h2*4);
    // --- B: wgT rows (k-contiguous f16) ---
    uint4 bv[8];
    #pragma unroll
    for (int i = 0; i < 8; i++){
      int c = i*256 + t;
      bv[i] = *(const uint4*)(wgT + (size_t)(c >> 3) * NN + kbase + kt + (c & 7) * 8);
    }
    // --- mix 3 graphs in f32, split into f16 hi + lo ---
    f16 hi8[8], lo8[8];
    #pragma unroll
    for (int j = 0; j < 8; j++){
      int h2 = j >> 2, jj = j & 3;
      float v = wa0*g[0][h2][jj] + wa1*g[1][h2][jj] + wa2*g[2][h2][jj];
      f16 h = (f16)v;
      hi8[j] = h;
      lo8[j] = (f16)(v - (float)h);
    }
    *(uint4*)&sm.s.Ah[ar*LD1 + kc] = *(const uint4*)hi8;
    *(uint4*)&sm.s.Al[ar*LD1 + kc] = *(const uint4*)lo8;
    #pragma unroll
    for (int i = 0; i < 8; i++){
      int c = i*256 + t;
      *(uint4*)&sm.s.B[(c >> 3)*LD1 + (c & 7)*8] = bv[i];
    }
    __syncthreads();
    #pragma unroll
    for (int kk = 0; kk < 2; kk++){
      f16x8 ah = ld_f16x8(&sm.s.Ah[(mh*16 + qm)*LD1 + kk*32 + quad*8]);
      f16x8 al = ld_f16x8(&sm.s.Al[(mh*16 + qm)*LD1 + kk*32 + quad*8]);
      #pragma unroll
      for (int tn = 0; tn < 8; tn++){
        f16x8 b = ld_f16x8(&sm.s.B[(nh*128 + tn*16 + qm)*LD1 + kk*32 + quad*8]);
        acc[tn] = __builtin_amdgcn_mfma_f32_16x16x32_f16(ah, b, acc[tn], 0, 0, 0);
        acc[tn] = __builtin_amdgcn_mfma_f32_16x16x32_f16(al, b, acc[tn], 0, 0, 0);
      }
    }
    __syncthreads();
  }

  // epilogue: LDS transpose 32x256 f32 tile, coalesced atomicAdd into W2T
  #pragma unroll
  for (int tn = 0; tn < 8; tn++)
    #pragma unroll
    for (int r = 0; r < 4; r++)
      sm.T[(mh*16 + quad*4 + r)*257 + nh*128 + tn*16 + qm] = acc[tn][r];
  __syncthreads();
  const int ui = t >> 5, ii = t & 31;
  #pragma unroll 4
  for (int rep = 0; rep < 32; rep++){
    int u = rep*8 + ui;
    atomicAdd(&W2T[(size_t)u * NN + mbase + ii], sm.T[ii*257 + u]);
  }
}

// ---------------- Kcvt: W2T f32 -> f16 -----------------------------
__global__ __launch_bounds__(256) void k_cvt(
    const float* __restrict__ W2T, f16* __restrict__ W2Th)
{
  size_t base = ((size_t)blockIdx.x * 256 + threadIdx.x) * 8;
  f32x4 a = *(const f32x4*)(W2T + base);
  f32x4 b = *(const f32x4*)(W2T + base + 4);
  f16 o[8];
  #pragma unroll
  for (int j = 0; j < 4; j++){ o[j] = (f16)a[j]; o[4+j] = (f16)b[j]; }
  *(uint4*)(W2Th + base) = *(const uint4*)o;
}

// ---------------- K2: x = relu(inputs @ W2), f32 out ---------------
// A = inputs (f32, split f16 hi+lo), B = W2Th (f16). 16m x 128n tiles.
#define LD2 72
__global__ __launch_bounds__(256) void k2_x(
    const float* __restrict__ inputs, const f16* __restrict__ W2Th,
    float* __restrict__ xbuf)
{
  __shared__ struct { f16 Ah[16*LD2]; f16 Al[16*LD2]; f16 B[128*LD2]; } sm;
  const int m0 = blockIdx.x * 16, n0 = blockIdx.y * 128;
  const int t = threadIdx.x, lane = t & 63, wv = t >> 6;
  const int qm = lane & 15, quad = lane >> 4;
  f32x4 acc[2] = { zero4(), zero4() };

  const int ar = t >> 4;           // 0..15
  const int kc4 = (t & 15) * 4;    // 0..60
  const float* pa = inputs + (size_t)(m0 + ar) * NN + kc4;

  for (int kt = 0; kt < 4096; kt += 64){
    f32x4 av = *(const f32x4*)(pa + kt);
    uint4 bv[4];
    #pragma unroll
    for (int i = 0; i < 4; i++){
      int c = i*256 + t;
      bv[i] = *(const uint4*)(W2Th + (size_t)(n0 + (c >> 3)) * NN + kt + (c & 7) * 8);
    }
    f16 hi[4], lo[4];
    #pragma unroll
    for (int j = 0; j < 4; j++){
      f16 h = (f16)av[j]; hi[j] = h; lo[j] = (f16)(av[j] - (float)h);
    }
    *(uint2*)&sm.Ah[ar*LD2 + kc4] = *(const uint2*)hi;
    *(uint2*)&sm.Al[ar*LD2 + kc4] = *(const uint2*)lo;
    #pragma unroll
    for (int i = 0; i < 4; i++){
      int c = i*256 + t;
      *(uint4*)&sm.B[(c >> 3)*LD2 + (c & 7)*8] = bv[i];
    }
    __syncthreads();
    #pragma unroll
    for (int kk = 0; kk < 2; kk++){
      f16x8 ah = ld_f16x8(&sm.Ah[qm*LD2 + kk*32 + quad*8]);
      f16x8 al = ld_f16x8(&sm.Al[qm*LD2 + kk*32 + quad*8]);
      #pragma unroll
      for (int tn = 0; tn < 2; tn++){
        f16x8 b = ld_f16x8(&sm.B[(wv*32 + tn*16 + qm)*LD2 + kk*32 + quad*8]);
        acc[tn] = __builtin_amdgcn_mfma_f32_16x16x32_f16(ah, b, acc[tn], 0, 0, 0);
        acc[tn] = __builtin_amdgcn_mfma_f32_16x16x32_f16(al, b, acc[tn], 0, 0, 0);
      }
    }
    __syncthreads();
  }
  #pragma unroll
  for (int tn = 0; tn < 2; tn++)
    #pragma unroll
    for (int r = 0; r < 4; r++)
      xbuf[(size_t)(m0 + quad*4 + r) * UN + n0 + wv*32 + tn*16 + qm] =
          fmaxf(acc[tn][r], 0.f);
}

// ---------------- K3: GRU gates + output, pure f32 VALU ------------
// block = 256 threads (thread t -> unit n=t), 4 batch rows per block.
__global__ __launch_bounds__(256) void k3_gru(
    const float* __restrict__ xbuf, const float* __restrict__ state,
    const float* __restrict__ wz, const float* __restrict__ uz,
    const float* __restrict__ bz,
    const float* __restrict__ wh, const float* __restrict__ uh,
    const float* __restrict__ bh,
    float* __restrict__ out)
{
  __shared__ float xs[4][256], ss[4][256];
  const int m0 = blockIdx.x * 4;
  const int t = threadIdx.x;
  #pragma unroll
  for (int i = 0; i < 4; i++){
    xs[i][t] = xbuf[(size_t)(m0 + i) * UN + t];
    ss[i][t] = state[(size_t)(m0 + i) * UN + t];
  }
  __syncthreads();
  float az[4], ah[4];
  const float bzv = bz[t], bhv = bh[t];
  #pragma unroll
  for (int m = 0; m < 4; m++){ az[m] = bzv; ah[m] = bhv; }
  for (int k = 0; k < 256; k++){
    float wzv = wz[(size_t)k * UN + t];
    float whv = wh[(size_t)k * UN + t];
    #pragma unroll
    for (int m = 0; m < 4; m++){
      az[m] = fmaf(xs[m][k], wzv, az[m]);
      ah[m] = fmaf(xs[m][k], whv, ah[m]);
    }
  }
  for (int k = 0; k < 256; k++){
    float uzv = uz[(size_t)k * UN + t];
    float uhv = uh[(size_t)k * UN + t];
    #pragma unroll
    for (int m = 0; m < 4; m++){
      az[m] = fmaf(ss[m][k], uzv, az[m]);
      ah[m] = fmaf(ss[m][k], uhv, ah[m]);
    }
  }
  #pragma unroll
  for (int m = 0; m < 4; m++){
    float z = 1.f / (1.f + __expf(-az[m]));
    float e = __expf(2.f * ah[m]);
    float h = 1.f - 2.f / (e + 1.f);      // tanh, saturation-safe
    out[(size_t)(m0 + m) * UN + t] = (1.f - z) * ss[m][t] + z * h;
  }
}

// ---------------- launch ------------------------------------------
extern "C" void kernel_launch(void* const* d_in, const int* in_sizes, int n_in,
                              void* d_out, int out_size, void* d_ws, size_t ws_size,
                              hipStream_t stream)
{
  const float* inputs = (const float*)d_in[0];
  const float* state  = (const float*)d_in[1];
  const float* adj    = (const float*)d_in[2];
  const float* wa     = (const float*)d_in[3];
  const float* wg     = (const float*)d_in[4];
  const float* wz     = (const float*)d_in[5];
  const float* uz     = (const float*)d_in[6];
  const float* bz     = (const float*)d_in[7];
  const float* wh     = (const float*)d_in[8];
  const float* uh     = (const float*)d_in[9];
  const float* bh     = (const float*)d_in[10];
  float* out = (float*)d_out;

  char* ws = (char*)d_ws;
  float* W2T  = (float*)(ws);                 // 4 MB   [256][4096] f32
  f16*   wgT  = (f16*)(ws + (4u<<20));        // 2 MB   [256][4096] f16
  f16*   W2Th = (f16*)(ws + (6u<<20));        // 2 MB   [256][4096] f16
  float* xbuf = (float*)(ws + (8u<<20));      // 512 KB [512][256]  f32

  hipMemsetAsync(W2T, 0, (size_t)NN * UN * sizeof(float), stream);
  k0_wgT<<<1024, 256, 0, stream>>>(wg, wgT);
  k1_w2t<<<dim3(128, 4), 256, 0, stream>>>(adj, wa, wgT, W2T);
  k_cvt<<<512, 256, 0, stream>>>(W2T, W2Th);
  k2_x<<<dim3(32, 2), 256, 0, stream>>>(inputs, W2Th, xbuf);
  k3_gru<<<128, 256, 0, stream>>>(xbuf, state, wz, uz, bz, wh, uh, bh, out);
}

// Round 4
// 411.294 us; speedup vs baseline: 1.5333x; 1.5333x over previous
//
#include <hip/hip_runtime.h>
#include <stdint.h>

typedef _Float16 f16;
typedef __attribute__((ext_vector_type(8))) _Float16 f16x8;
typedef __attribute__((ext_vector_type(4))) float f32x4;

#define NN 4096
#define UN 256

__device__ __forceinline__ f16x8 ld_f16x8(const f16* p){ return *(const f16x8*)p; }
__device__ __forceinline__ f32x4 zero4(){ f32x4 z = {0.f,0.f,0.f,0.f}; return z; }

// ---------------- K0: transposes into workspace -------------------
// b<1024: wgT[256][4096] = (f16) w_gcn^T
// b>=1024: gate weights -> czT_h/l [256 n][512 k] (k<256 from wz, k>=256 from uz),
//          chT_h/l likewise from wh/uh. f16 hi + lo split.
__global__ __launch_bounds__(256) void k0_transpose(
    const float* __restrict__ wg, const float* __restrict__ wz,
    const float* __restrict__ uz, const float* __restrict__ wh,
    const float* __restrict__ uh,
    f16* __restrict__ wgT,
    f16* __restrict__ czT_h, f16* __restrict__ czT_l,
    f16* __restrict__ chT_h, f16* __restrict__ chT_l)
{
  __shared__ float tile[32][33];
  const int b = blockIdx.x;
  const int tx = threadIdx.x & 31, ty = threadIdx.x >> 5;
  if (b < 1024){
    const int tr = b >> 3, tc = b & 7;
    const int r0 = tr * 32, c0 = tc * 32;   // r0: node(k), c0: unit(n)
    #pragma unroll
    for (int i = 0; i < 4; i++){
      int r = ty + i*8;
      tile[r][tx] = wg[(size_t)(r0 + r) * UN + c0 + tx];
    }
    __syncthreads();
    #pragma unroll
    for (int i = 0; i < 4; i++){
      int r = ty + i*8;
      wgT[(size_t)(c0 + r) * NN + r0 + tx] = (f16)tile[tx][r];
    }
  } else {
    const int j = (b - 1024) >> 6;          // 0=wz 1=uz 2=wh 3=uh
    const int rem = (b - 1024) & 63;
    const int tr = rem >> 3, tc = rem & 7;
    const int r0 = tr * 32, c0 = tc * 32;   // r0: k, c0: n
    const float* src = (j==0) ? wz : (j==1) ? uz : (j==2) ? wh : uh;
    f16* dh = (j < 2) ? czT_h : chT_h;
    f16* dl = (j < 2) ? czT_l : chT_l;
    const int koff = (j & 1) ? 256 : 0;
    #pragma unroll
    for (int i = 0; i < 4; i++){
      int r = ty + i*8;
      tile[r][tx] = src[(size_t)(r0 + r) * UN + c0 + tx];
    }
    __syncthreads();
    #pragma unroll
    for (int i = 0; i < 4; i++){
      int r = ty + i*8;
      float v = tile[tx][r];                // = src[r0+tx][c0+r]
      f16 h = (f16)v;
      size_t o = (size_t)(c0 + r) * 512 + koff + r0 + tx;
      dh[o] = h;
      dl[o] = (f16)(v - (float)h);
    }
  }
}

// ---------------- K1: W2T[u][node] += (sum_g wa_g adj_g) @ w_gcn --
#define LD1 72
union K1S {
  struct { f16 Ah[32*LD1]; f16 Al[32*LD1]; f16 B[256*LD1]; } s;  // 46080 B
  float T[32*257];                                                // 32896 B
};

__global__ __launch_bounds__(256) void k1_w2t(
    const float* __restrict__ adj, const float* __restrict__ wa,
    const f16* __restrict__ wgT, float* __restrict__ W2T)
{
  __shared__ K1S sm;
  const int t = threadIdx.x;
  const int mbase = blockIdx.x * 32;
  const int kbase = blockIdx.y * 1024;
  const float wa0 = wa[0], wa1 = wa[1], wa2 = wa[2];
  const int lane = t & 63, wv = t >> 6;
  const int mh = wv & 1, nh = wv >> 1;
  const int qm = lane & 15, quad = lane >> 4;

  f32x4 acc[8] = { zero4(), zero4(), zero4(), zero4(),
                   zero4(), zero4(), zero4(), zero4() };

  const int ar = t >> 3;
  const int kc = (t & 7) * 8;
  const size_t gs = (size_t)NN * NN;
  const float* pa = adj + (size_t)(mbase + ar) * NN + kbase + kc;

  for (int kt = 0; kt < 1024; kt += 64){
    f32x4 g[3][2];
    #pragma unroll
    for (int g3 = 0; g3 < 3; g3++)
      #pragma unroll
      for (int h2 = 0; h2 < 2; h2++)
        g[g3][h2] = *(const f32x4*)(pa + kt + (size_t)g3*gs + h2*4);
    uint4 bv[8];
    #pragma unroll
    for (int i = 0; i < 8; i++){
      int c = i*256 + t;
      bv[i] = *(const uint4*)(wgT + (size_t)(c >> 3) * NN + kbase + kt + (c & 7) * 8);
    }
    f16 hi8[8], lo8[8];
    #pragma unroll
    for (int j = 0; j < 8; j++){
      int h2 = j >> 2, jj = j & 3;
      float v = wa0*g[0][h2][jj] + wa1*g[1][h2][jj] + wa2*g[2][h2][jj];
      f16 h = (f16)v;
      hi8[j] = h;
      lo8[j] = (f16)(v - (float)h);
    }
    *(uint4*)&sm.s.Ah[ar*LD1 + kc] = *(const uint4*)hi8;
    *(uint4*)&sm.s.Al[ar*LD1 + kc] = *(const uint4*)lo8;
    #pragma unroll
    for (int i = 0; i < 8; i++){
      int c = i*256 + t;
      *(uint4*)&sm.s.B[(c >> 3)*LD1 + (c & 7)*8] = bv[i];
    }
    __syncthreads();
    #pragma unroll
    for (int kk = 0; kk < 2; kk++){
      f16x8 ah = ld_f16x8(&sm.s.Ah[(mh*16 + qm)*LD1 + kk*32 + quad*8]);
      f16x8 al = ld_f16x8(&sm.s.Al[(mh*16 + qm)*LD1 + kk*32 + quad*8]);
      #pragma unroll
      for (int tn = 0; tn < 8; tn++){
        f16x8 b = ld_f16x8(&sm.s.B[(nh*128 + tn*16 + qm)*LD1 + kk*32 + quad*8]);
        acc[tn] = __builtin_amdgcn_mfma_f32_16x16x32_f16(ah, b, acc[tn], 0, 0, 0);
        acc[tn] = __builtin_amdgcn_mfma_f32_16x16x32_f16(al, b, acc[tn], 0, 0, 0);
      }
    }
    __syncthreads();
  }

  #pragma unroll
  for (int tn = 0; tn < 8; tn++)
    #pragma unroll
    for (int r = 0; r < 4; r++)
      sm.T[(mh*16 + quad*4 + r)*257 + nh*128 + tn*16 + qm] = acc[tn][r];
  __syncthreads();
  const int ui = t >> 5, ii = t & 31;
  #pragma unroll 4
  for (int rep = 0; rep < 32; rep++){
    int u = rep*8 + ui;
    atomicAdd(&W2T[(size_t)u * NN + mbase + ii], sm.T[ii*257 + u]);
  }
}

// ---------------- Kcvt: W2T f32 -> f16 -----------------------------
__global__ __launch_bounds__(256) void k_cvt(
    const float* __restrict__ W2T, f16* __restrict__ W2Th)
{
  size_t base = ((size_t)blockIdx.x * 256 + threadIdx.x) * 8;
  f32x4 a = *(const f32x4*)(W2T + base);
  f32x4 b = *(const f32x4*)(W2T + base + 4);
  f16 o[8];
  #pragma unroll
  for (int j = 0; j < 4; j++){ o[j] = (f16)a[j]; o[4+j] = (f16)b[j]; }
  *(uint4*)(W2Th + base) = *(const uint4*)o;
}

// ---------------- K2: xg += inputs @ W2 (K-split, f32 atomic) ------
#define LD2 72
__global__ __launch_bounds__(256) void k2_x(
    const float* __restrict__ inputs, const f16* __restrict__ W2Th,
    float* __restrict__ xg)
{
  __shared__ struct { f16 Ah[16*LD2]; f16 Al[16*LD2]; f16 B[128*LD2]; } sm;
  const int m0 = blockIdx.x * 16, n0 = blockIdx.y * 128;
  const int kbase = blockIdx.z * 1024;
  const int t = threadIdx.x, lane = t & 63, wv = t >> 6;
  const int qm = lane & 15, quad = lane >> 4;
  f32x4 acc[2] = { zero4(), zero4() };

  const int ar = t >> 4;
  const int kc4 = (t & 15) * 4;
  const float* pa = inputs + (size_t)(m0 + ar) * NN + kbase + kc4;

  for (int kt = 0; kt < 1024; kt += 64){
    f32x4 av = *(const f32x4*)(pa + kt);
    uint4 bv[4];
    #pragma unroll
    for (int i = 0; i < 4; i++){
      int c = i*256 + t;
      bv[i] = *(const uint4*)(W2Th + (size_t)(n0 + (c >> 3)) * NN + kbase + kt + (c & 7) * 8);
    }
    f16 hi[4], lo[4];
    #pragma unroll
    for (int j = 0; j < 4; j++){
      f16 h = (f16)av[j]; hi[j] = h; lo[j] = (f16)(av[j] - (float)h);
    }
    *(uint2*)&sm.Ah[ar*LD2 + kc4] = *(const uint2*)hi;
    *(uint2*)&sm.Al[ar*LD2 + kc4] = *(const uint2*)lo;
    #pragma unroll
    for (int i = 0; i < 4; i++){
      int c = i*256 + t;
      *(uint4*)&sm.B[(c >> 3)*LD2 + (c & 7)*8] = bv[i];
    }
    __syncthreads();
    #pragma unroll
    for (int kk = 0; kk < 2; kk++){
      f16x8 ah = ld_f16x8(&sm.Ah[qm*LD2 + kk*32 + quad*8]);
      f16x8 al = ld_f16x8(&sm.Al[qm*LD2 + kk*32 + quad*8]);
      #pragma unroll
      for (int tn = 0; tn < 2; tn++){
        f16x8 b = ld_f16x8(&sm.B[(wv*32 + tn*16 + qm)*LD2 + kk*32 + quad*8]);
        acc[tn] = __builtin_amdgcn_mfma_f32_16x16x32_f16(ah, b, acc[tn], 0, 0, 0);
        acc[tn] = __builtin_amdgcn_mfma_f32_16x16x32_f16(al, b, acc[tn], 0, 0, 0);
      }
    }
    __syncthreads();
  }
  #pragma unroll
  for (int tn = 0; tn < 2; tn++)
    #pragma unroll
    for (int r = 0; r < 4; r++)
      atomicAdd(&xg[(size_t)(m0 + quad*4 + r) * UN + n0 + wv*32 + tn*16 + qm],
                acc[tn][r]);
}

// ---------------- K2b: xa = f16 hi/lo of [relu(xg) | state] --------
__global__ __launch_bounds__(256) void k2b_xa(
    const float* __restrict__ xg, const float* __restrict__ state,
    f16* __restrict__ xa_h, f16* __restrict__ xa_l)
{
  const size_t e = ((size_t)blockIdx.x * 256 + threadIdx.x) * 8;
  const int m = (int)(e >> 9), k0 = (int)(e & 511);
  const float* src = (k0 < 256) ? (xg + (size_t)m * UN + k0)
                                : (state + (size_t)m * UN + (k0 - 256));
  f32x4 a = *(const f32x4*)src;
  f32x4 b = *(const f32x4*)(src + 4);
  const bool rl = (k0 < 256);
  f16 hi[8], lo[8];
  #pragma unroll
  for (int j = 0; j < 4; j++){
    float va = rl ? fmaxf(a[j], 0.f) : a[j];
    float vb = rl ? fmaxf(b[j], 0.f) : b[j];
    f16 ha = (f16)va, hb = (f16)vb;
    hi[j] = ha;   lo[j] = (f16)(va - (float)ha);
    hi[4+j] = hb; lo[4+j] = (f16)(vb - (float)hb);
  }
  *(uint4*)(xa_h + e) = *(const uint4*)hi;
  *(uint4*)(xa_l + e) = *(const uint4*)lo;
}

// ---------------- K3: GRU gates via MFMA, no LDS -------------------
// grid: 32 m-tiles of 16. Wave wv -> n-quarter of 64. K = 512.
__global__ __launch_bounds__(256) void k3_gru(
    const f16* __restrict__ xa_h, const f16* __restrict__ xa_l,
    const f16* __restrict__ czT_h, const f16* __restrict__ czT_l,
    const f16* __restrict__ chT_h, const f16* __restrict__ chT_l,
    const float* __restrict__ bz, const float* __restrict__ bh,
    const float* __restrict__ state, float* __restrict__ out)
{
  const int m0 = blockIdx.x * 16;
  const int t = threadIdx.x, lane = t & 63, wv = t >> 6;
  const int qm = lane & 15, quad = lane >> 4;
  const int n0 = wv * 64;
  f32x4 az[4] = { zero4(), zero4(), zero4(), zero4() };
  f32x4 ag[4] = { zero4(), zero4(), zero4(), zero4() };

  const f16* pah = xa_h + (size_t)(m0 + qm) * 512 + quad*8;
  const f16* pal = xa_l + (size_t)(m0 + qm) * 512 + quad*8;

  #pragma unroll 2
  for (int k0 = 0; k0 < 512; k0 += 32){
    f16x8 a_h = ld_f16x8(pah + k0);
    f16x8 a_l = ld_f16x8(pal + k0);
    #pragma unroll
    for (int tn = 0; tn < 4; tn++){
      const size_t bo = (size_t)(n0 + tn*16 + qm) * 512 + k0 + quad*8;
      f16x8 bzh = ld_f16x8(czT_h + bo);
      f16x8 bzl = ld_f16x8(czT_l + bo);
      f16x8 bhh = ld_f16x8(chT_h + bo);
      f16x8 bhl = ld_f16x8(chT_l + bo);
      az[tn] = __builtin_amdgcn_mfma_f32_16x16x32_f16(a_h, bzh, az[tn], 0, 0, 0);
      az[tn] = __builtin_amdgcn_mfma_f32_16x16x32_f16(a_l, bzh, az[tn], 0, 0, 0);
      az[tn] = __builtin_amdgcn_mfma_f32_16x16x32_f16(a_h, bzl, az[tn], 0, 0, 0);
      ag[tn] = __builtin_amdgcn_mfma_f32_16x16x32_f16(a_h, bhh, ag[tn], 0, 0, 0);
      ag[tn] = __builtin_amdgcn_mfma_f32_16x16x32_f16(a_l, bhh, ag[tn], 0, 0, 0);
      ag[tn] = __builtin_amdgcn_mfma_f32_16x16x32_f16(a_h, bhl, ag[tn], 0, 0, 0);
    }
  }

  #pragma unroll
  for (int tn = 0; tn < 4; tn++){
    const int n = n0 + tn*16 + qm;
    const float bzv = bz[n], bhv = bh[n];
    #pragma unroll
    for (int r = 0; r < 4; r++){
      const int m = m0 + quad*4 + r;
      float zl = az[tn][r] + bzv;
      float hl = ag[tn][r] + bhv;
      float z = 1.f / (1.f + __expf(-zl));
      float e = __expf(2.f * hl);
      float h = 1.f - 2.f / (e + 1.f);
      float s = state[(size_t)m * UN + n];
      out[(size_t)m * UN + n] = (1.f - z) * s + z * h;
    }
  }
}

// ---------------- launch ------------------------------------------
extern "C" void kernel_launch(void* const* d_in, const int* in_sizes, int n_in,
                              void* d_out, int out_size, void* d_ws, size_t ws_size,
                              hipStream_t stream)
{
  const float* inputs = (const float*)d_in[0];
  const float* state  = (const float*)d_in[1];
  const float* adj    = (const float*)d_in[2];
  const float* wa     = (const float*)d_in[3];
  const float* wg     = (const float*)d_in[4];
  const float* wz     = (const float*)d_in[5];
  const float* uz     = (const float*)d_in[6];
  const float* bz     = (const float*)d_in[7];
  const float* wh     = (const float*)d_in[8];
  const float* uh     = (const float*)d_in[9];
  const float* bh     = (const float*)d_in[10];
  float* out = (float*)d_out;

  char* ws = (char*)d_ws;
  float* W2T   = (float*)(ws);                                 // 4 MB   [256][4096] f32
  float* xg    = (float*)(ws + (4u<<20));                      // 512 KB [512][256]  f32
  f16*   wgT   = (f16*)(ws + (4u<<20) + (512u<<10));           // 2 MB   [256][4096]
  f16*   W2Th  = (f16*)(ws + (6u<<20) + (512u<<10));           // 2 MB   [256][4096]
  f16*   xa_h  = (f16*)(ws + (8u<<20) + (512u<<10));           // 512 KB [512][512]
  f16*   xa_l  = (f16*)(ws + (9u<<20));                        // 512 KB
  f16*   czT_h = (f16*)(ws + (9u<<20) + (512u<<10));           // 256 KB [256][512]
  f16*   czT_l = (f16*)(ws + (9u<<20) + (768u<<10));           // 256 KB
  f16*   chT_h = (f16*)(ws + (10u<<20));                       // 256 KB
  f16*   chT_l = (f16*)(ws + (10u<<20) + (256u<<10));          // 256 KB

  // zero W2T + xg (contiguous 4.5 MB)
  hipMemsetAsync(ws, 0, (4u<<20) + (512u<<10), stream);
  k0_transpose<<<1280, 256, 0, stream>>>(wg, wz, uz, wh, uh,
                                         wgT, czT_h, czT_l, chT_h, chT_l);
  k1_w2t<<<dim3(128, 4), 256, 0, stream>>>(adj, wa, wgT, W2T);
  k_cvt<<<512, 256, 0, stream>>>(W2T, W2Th);
  k2_x<<<dim3(32, 2, 4), 256, 0, stream>>>(inputs, W2Th, xg);
  k2b_xa<<<128, 256, 0, stream>>>(xg, state, xa_h, xa_l);
  k3_gru<<<32, 256, 0, stream>>>(xa_h, xa_l, czT_h, czT_l, chT_h, chT_l,
                                 bz, bh, state, out);
}

// Round 5
// 404.401 us; speedup vs baseline: 1.5594x; 1.0170x over previous
//
#include <hip/hip_runtime.h>
#include <stdint.h>

typedef _Float16 f16;
typedef __attribute__((ext_vector_type(8))) _Float16 f16x8;
typedef __attribute__((ext_vector_type(4))) float f32x4;

#define NN 4096
#define UN 256

__device__ __forceinline__ f16x8 ld_f16x8(const f16* p){ return *(const f16x8*)p; }
__device__ __forceinline__ f32x4 zero4(){ f32x4 z = {0.f,0.f,0.f,0.f}; return z; }

// Fragment-major B layout: [k/32][n/16][lane=((k>>3)&3)*16+(n&15)][j=k&7] f16.
// A wave loads fragment (kc,nt) as one coalesced 1KB read: base + lane*8.

// ---------------- K0: build wgB (f16 frag-major) + gate frag buffers ------
// blocks 0..127:  wgB from wg [4096 k][256 n] f32
// blocks 128..143: czB_h/l from [wz;uz], chB_h/l from [wh;uh]  (K=512)
__global__ __launch_bounds__(256) void k0_prep(
    const float* __restrict__ wg, const float* __restrict__ wz,
    const float* __restrict__ uz, const float* __restrict__ wh,
    const float* __restrict__ uh,
    f16* __restrict__ wgB,
    f16* __restrict__ czB_h, f16* __restrict__ czB_l,
    f16* __restrict__ chB_h, f16* __restrict__ chB_l)
{
  __shared__ float lsA[32*256];
  __shared__ float lsB[32*256];
  const int t = threadIdx.x;
  const int b = blockIdx.x;
  if (b < 128){
    const int kcg = b;
    #pragma unroll 8
    for (int i = 0; i < 32; i++)
      lsA[i*256 + t] = wg[(size_t)(kcg*32 + i) * UN + t];
    __syncthreads();
    #pragma unroll
    for (int i = 0; i < 4; i++){
      int o = i*256 + t;               // 0..1023 fragment-octet index
      int l = o & 63;
      int n = ((o >> 6) << 4) + (l & 15);
      int kl = (l >> 4) * 8;
      f16 v8[8];
      #pragma unroll
      for (int j = 0; j < 8; j++) v8[j] = (f16)lsA[(kl + j)*256 + n];
      *(uint4*)(wgB + ((size_t)kcg*1024 + o)*8) = *(const uint4*)v8;
    }
  } else {
    const int kcg = b - 128;           // 0..15, K=512
    #pragma unroll 8
    for (int i = 0; i < 32; i++){
      int kg = kcg*32 + i;
      lsA[i*256 + t] = (kg < 256) ? wz[(size_t)kg * UN + t]
                                  : uz[(size_t)(kg - 256) * UN + t];
      lsB[i*256 + t] = (kg < 256) ? wh[(size_t)kg * UN + t]
                                  : uh[(size_t)(kg - 256) * UN + t];
    }
    __syncthreads();
    #pragma unroll
    for (int i = 0; i < 4; i++){
      int o = i*256 + t;
      int l = o & 63;
      int n = ((o >> 6) << 4) + (l & 15);
      int kl = (l >> 4) * 8;
      f16 zh[8], zl[8], hh[8], hl[8];
      #pragma unroll
      for (int j = 0; j < 8; j++){
        float vz = lsA[(kl + j)*256 + n];
        float vh = lsB[(kl + j)*256 + n];
        f16 a = (f16)vz; zh[j] = a; zl[j] = (f16)(vz - (float)a);
        f16 c = (f16)vh; hh[j] = c; hl[j] = (f16)(vh - (float)c);
      }
      size_t off = ((size_t)kcg*1024 + o)*8;
      *(uint4*)(czB_h + off) = *(const uint4*)zh;
      *(uint4*)(czB_l + off) = *(const uint4*)zl;
      *(uint4*)(chB_h + off) = *(const uint4*)hh;
      *(uint4*)(chB_l + off) = *(const uint4*)hl;
    }
  }
}

// ---------------- K1: W2[node][unit] += (sum_g wa_g adj_g) @ w_gcn --------
// No LDS, no barriers. Block = 4 waves x 16 rows = 64-row M-tile, N=256 full.
// Grid (64 m-tiles, 8 k-splits). A per-lane direct loads; B frag-major.
__global__ __launch_bounds__(256) void k1_w2(
    const float* __restrict__ adj, const float* __restrict__ wa,
    const f16* __restrict__ wgB, float* __restrict__ W2)
{
  const int t = threadIdx.x, lane = t & 63, wv = t >> 6;
  const int qm = lane & 15, quad = lane >> 4;
  const int mbase = blockIdx.x * 64 + wv * 16;
  const int kbase = blockIdx.y * 512;
  const float wa0 = wa[0], wa1 = wa[1], wa2 = wa[2];
  const size_t gs = (size_t)NN * NN;
  const float* pa = adj + (size_t)(mbase + qm) * NN + kbase + quad * 8;

  f32x4 acc[16];
  #pragma unroll
  for (int i = 0; i < 16; i++) acc[i] = zero4();

  for (int kc = 0; kc < 512; kc += 32){
    f32x4 g0a = *(const f32x4*)(pa + kc);
    f32x4 g0b = *(const f32x4*)(pa + kc + 4);
    f32x4 g1a = *(const f32x4*)(pa + kc + gs);
    f32x4 g1b = *(const f32x4*)(pa + kc + gs + 4);
    f32x4 g2a = *(const f32x4*)(pa + kc + 2*gs);
    f32x4 g2b = *(const f32x4*)(pa + kc + 2*gs + 4);
    f16x8 ah, al;
    #pragma unroll
    for (int j = 0; j < 4; j++){
      float v0 = wa0*g0a[j] + wa1*g1a[j] + wa2*g2a[j];
      float v1 = wa0*g0b[j] + wa1*g1b[j] + wa2*g2b[j];
      f16 h0 = (f16)v0, h1 = (f16)v1;
      ah[j] = h0;   al[j] = (f16)(v0 - (float)h0);
      ah[4+j] = h1; al[4+j] = (f16)(v1 - (float)h1);
    }
    const int kcg = (kbase + kc) >> 5;
    const f16* pb = wgB + ((size_t)kcg*1024 + lane)*8;
    #pragma unroll
    for (int tn = 0; tn < 16; tn++){
      f16x8 bfr = ld_f16x8(pb + tn*512);
      acc[tn] = __builtin_amdgcn_mfma_f32_16x16x32_f16(ah, bfr, acc[tn], 0, 0, 0);
      acc[tn] = __builtin_amdgcn_mfma_f32_16x16x32_f16(al, bfr, acc[tn], 0, 0, 0);
    }
  }
  // epilogue: D[m=quad*4+r][n=tn*16+qm]; 64B-coalesced f32 atomics
  #pragma unroll
  for (int tn = 0; tn < 16; tn++)
    #pragma unroll
    for (int r = 0; r < 4; r++)
      atomicAdd(&W2[(size_t)(mbase + quad*4 + r)*UN + tn*16 + qm], acc[tn][r]);
}

// ---------------- Kcvt: W2 f32 [4096][256] -> W2B f16 frag-major ----------
__global__ __launch_bounds__(256) void k_cvt(
    const float* __restrict__ W2, f16* __restrict__ W2B)
{
  __shared__ float ls[32*256];
  const int t = threadIdx.x;
  const int kcg = blockIdx.x;            // 0..127
  #pragma unroll 8
  for (int i = 0; i < 32; i++)
    ls[i*256 + t] = W2[(size_t)(kcg*32 + i) * UN + t];
  __syncthreads();
  #pragma unroll
  for (int i = 0; i < 4; i++){
    int o = i*256 + t;
    int l = o & 63;
    int n = ((o >> 6) << 4) + (l & 15);
    int kl = (l >> 4) * 8;
    f16 v8[8];
    #pragma unroll
    for (int j = 0; j < 8; j++) v8[j] = (f16)ls[(kl + j)*256 + n];
    *(uint4*)(W2B + ((size_t)kcg*1024 + o)*8) = *(const uint4*)v8;
  }
}

// ---------------- K2: xg[m][n] += inputs @ W2 -----------------------------
// Block = 16-row M-tile, 4 waves = n-quarters. Grid (32 m, 32 k-splits of 128).
__global__ __launch_bounds__(256) void k2_x(
    const float* __restrict__ inputs, const f16* __restrict__ W2B,
    float* __restrict__ xg)
{
  const int t = threadIdx.x, lane = t & 63, wv = t >> 6;
  const int qm = lane & 15, quad = lane >> 4;
  const int m0 = blockIdx.x * 16;
  const int kbase = blockIdx.y * 128;
  const float* pa = inputs + (size_t)(m0 + qm) * NN + kbase + quad * 8;

  f32x4 acc[4] = { zero4(), zero4(), zero4(), zero4() };

  for (int kc = 0; kc < 128; kc += 32){
    f32x4 a0 = *(const f32x4*)(pa + kc);
    f32x4 a1 = *(const f32x4*)(pa + kc + 4);
    f16x8 ah, al;
    #pragma unroll
    for (int j = 0; j < 4; j++){
      f16 h0 = (f16)a0[j], h1 = (f16)a1[j];
      ah[j] = h0;   al[j] = (f16)(a0[j] - (float)h0);
      ah[4+j] = h1; al[4+j] = (f16)(a1[j] - (float)h1);
    }
    const int kcg = (kbase + kc) >> 5;
    const f16* pb = W2B + (((size_t)kcg*16 + wv*4)*64 + lane)*8;
    #pragma unroll
    for (int tn = 0; tn < 4; tn++){
      f16x8 bfr = ld_f16x8(pb + tn*512);
      acc[tn] = __builtin_amdgcn_mfma_f32_16x16x32_f16(ah, bfr, acc[tn], 0, 0, 0);
      acc[tn] = __builtin_amdgcn_mfma_f32_16x16x32_f16(al, bfr, acc[tn], 0, 0, 0);
    }
  }
  #pragma unroll
  for (int tn = 0; tn < 4; tn++)
    #pragma unroll
    for (int r = 0; r < 4; r++)
      atomicAdd(&xg[(size_t)(m0 + quad*4 + r)*UN + (wv*4 + tn)*16 + qm],
                acc[tn][r]);
}

// ---------------- K2b: xa = f16 hi/lo of [relu(xg) | state] ---------------
__global__ __launch_bounds__(256) void k2b_xa(
    const float* __restrict__ xg, const float* __restrict__ state,
    f16* __restrict__ xa_h, f16* __restrict__ xa_l)
{
  const size_t e = ((size_t)blockIdx.x * 256 + threadIdx.x) * 8;
  const int m = (int)(e >> 9), k0 = (int)(e & 511);
  const float* src = (k0 < 256) ? (xg + (size_t)m * UN + k0)
                                : (state + (size_t)m * UN + (k0 - 256));
  f32x4 a = *(const f32x4*)src;
  f32x4 b = *(const f32x4*)(src + 4);
  const bool rl = (k0 < 256);
  f16 hi[8], lo[8];
  #pragma unroll
  for (int j = 0; j < 4; j++){
    float va = rl ? fmaxf(a[j], 0.f) : a[j];
    float vb = rl ? fmaxf(b[j], 0.f) : b[j];
    f16 ha = (f16)va, hb = (f16)vb;
    hi[j] = ha;   lo[j] = (f16)(va - (float)ha);
    hi[4+j] = hb; lo[4+j] = (f16)(vb - (float)hb);
  }
  *(uint4*)(xa_h + e) = *(const uint4*)hi;
  *(uint4*)(xa_l + e) = *(const uint4*)lo;
}

// ---------------- K3: gate logits via MFMA, K-split ----------------------
// Grid (32 m-tiles of 16, 8 k-splits of 64). Waves = n-quarters. Both gates.
__global__ __launch_bounds__(256) void k3_gates(
    const f16* __restrict__ xa_h, const f16* __restrict__ xa_l,
    const f16* __restrict__ czB_h, const f16* __restrict__ czB_l,
    const f16* __restrict__ chB_h, const f16* __restrict__ chB_l,
    float* __restrict__ lz, float* __restrict__ lh)
{
  const int t = threadIdx.x, lane = t & 63, wv = t >> 6;
  const int qm = lane & 15, quad = lane >> 4;
  const int m0 = blockIdx.x * 16;
  const int kbase = blockIdx.y * 64;
  const size_t pao = (size_t)(m0 + qm) * 512 + kbase + quad * 8;

  f32x4 az[4] = { zero4(), zero4(), zero4(), zero4() };
  f32x4 ag[4] = { zero4(), zero4(), zero4(), zero4() };

  #pragma unroll
  for (int kc = 0; kc < 64; kc += 32){
    f16x8 ah = ld_f16x8(xa_h + pao + kc);
    f16x8 al = ld_f16x8(xa_l + pao + kc);
    const int kcg = (kbase + kc) >> 5;
    const size_t base = (((size_t)kcg*16 + wv*4)*64 + lane)*8;
    #pragma unroll
    for (int tn = 0; tn < 4; tn++){
      f16x8 bzh = ld_f16x8(czB_h + base + tn*512);
      f16x8 bzl = ld_f16x8(czB_l + base + tn*512);
      f16x8 bhh = ld_f16x8(chB_h + base + tn*512);
      f16x8 bhl = ld_f16x8(chB_l + base + tn*512);
      az[tn] = __builtin_amdgcn_mfma_f32_16x16x32_f16(ah, bzh, az[tn], 0, 0, 0);
      az[tn] = __builtin_amdgcn_mfma_f32_16x16x32_f16(al, bzh, az[tn], 0, 0, 0);
      az[tn] = __builtin_amdgcn_mfma_f32_16x16x32_f16(ah, bzl, az[tn], 0, 0, 0);
      ag[tn] = __builtin_amdgcn_mfma_f32_16x16x32_f16(ah, bhh, ag[tn], 0, 0, 0);
      ag[tn] = __builtin_amdgcn_mfma_f32_16x16x32_f16(al, bhh, ag[tn], 0, 0, 0);
      ag[tn] = __builtin_amdgcn_mfma_f32_16x16x32_f16(ah, bhl, ag[tn], 0, 0, 0);
    }
  }
  #pragma unroll
  for (int tn = 0; tn < 4; tn++)
    #pragma unroll
    for (int r = 0; r < 4; r++){
      size_t o = (size_t)(m0 + quad*4 + r)*UN + (wv*4 + tn)*16 + qm;
      atomicAdd(&lz[o], az[tn][r]);
      atomicAdd(&lh[o], ag[tn][r]);
    }
}

// ---------------- K3b: elementwise gates + output -------------------------
__global__ __launch_bounds__(256) void k3b_out(
    const float* __restrict__ lz, const float* __restrict__ lh,
    const float* __restrict__ state,
    const float* __restrict__ bz, const float* __restrict__ bh,
    float* __restrict__ out)
{
  const size_t e = ((size_t)blockIdx.x * 256 + threadIdx.x) * 4;
  const int n = (int)(e & 255);
  f32x4 z4 = *(const f32x4*)(lz + e);
  f32x4 h4 = *(const f32x4*)(lh + e);
  f32x4 s4 = *(const f32x4*)(state + e);
  f32x4 bz4 = *(const f32x4*)(bz + n);
  f32x4 bh4 = *(const f32x4*)(bh + n);
  f32x4 o4;
  #pragma unroll
  for (int j = 0; j < 4; j++){
    float z = 1.f / (1.f + __expf(-(z4[j] + bz4[j])));
    float ex = __expf(2.f * (h4[j] + bh4[j]));
    float hh = 1.f - 2.f / (ex + 1.f);
    o4[j] = (1.f - z) * s4[j] + z * hh;
  }
  *(f32x4*)(out + e) = o4;
}

// ---------------- launch --------------------------------------------------
extern "C" void kernel_launch(void* const* d_in, const int* in_sizes, int n_in,
                              void* d_out, int out_size, void* d_ws, size_t ws_size,
                              hipStream_t stream)
{
  const float* inputs = (const float*)d_in[0];
  const float* state  = (const float*)d_in[1];
  const float* adj    = (const float*)d_in[2];
  const float* wa     = (const float*)d_in[3];
  const float* wg     = (const float*)d_in[4];
  const float* wz     = (const float*)d_in[5];
  const float* uz     = (const float*)d_in[6];
  const float* bz     = (const float*)d_in[7];
  const float* wh     = (const float*)d_in[8];
  const float* uh     = (const float*)d_in[9];
  const float* bh     = (const float*)d_in[10];
  float* out = (float*)d_out;

  char* ws = (char*)d_ws;
  float* W2    = (float*)(ws);                          // 4 MB [4096][256] f32
  float* xg    = (float*)(ws + (4u<<20));               // 512 KB [512][256]
  float* lz    = (float*)(ws + (4u<<20) + (512u<<10));  // 512 KB
  float* lh    = (float*)(ws + (5u<<20));               // 512 KB
  f16* wgB     = (f16*)(ws + (5u<<20) + (512u<<10));    // 2 MB frag-major
  f16* W2B     = (f16*)(ws + (7u<<20) + (512u<<10));    // 2 MB frag-major
  f16* xa_h    = (f16*)(ws + (9u<<20) + (512u<<10));    // 512 KB [512][512]
  f16* xa_l    = (f16*)(ws + (10u<<20));                // 512 KB
  f16* czB_h   = (f16*)(ws + (10u<<20) + (512u<<10));   // 256 KB
  f16* czB_l   = (f16*)(ws + (10u<<20) + (768u<<10));   // 256 KB
  f16* chB_h   = (f16*)(ws + (11u<<20));                // 256 KB
  f16* chB_l   = (f16*)(ws + (11u<<20) + (256u<<10));   // 256 KB

  // zero W2 + xg + lz + lh (contiguous 5.5 MB)
  hipMemsetAsync(ws, 0, (5u<<20) + (512u<<10), stream);
  k0_prep<<<144, 256, 0, stream>>>(wg, wz, uz, wh, uh,
                                   wgB, czB_h, czB_l, chB_h, chB_l);
  k1_w2<<<dim3(64, 8), 256, 0, stream>>>(adj, wa, wgB, W2);
  k_cvt<<<128, 256, 0, stream>>>(W2, W2B);
  k2_x<<<dim3(32, 32), 256, 0, stream>>>(inputs, W2B, xg);
  k2b_xa<<<128, 256, 0, stream>>>(xg, state, xa_h, xa_l);
  k3_gates<<<dim3(32, 8), 256, 0, stream>>>(xa_h, xa_l, czB_h, czB_l,
                                            chB_h, chB_l, lz, lh);
  k3b_out<<<128, 256, 0, stream>>>(lz, lh, state, bz, bh, out);
}

// Round 6
// 382.072 us; speedup vs baseline: 1.6505x; 1.0584x over previous
//
#include <hip/hip_runtime.h>
#include <stdint.h>

typedef _Float16 f16;
typedef __attribute__((ext_vector_type(8))) _Float16 f16x8;
typedef __attribute__((ext_vector_type(4))) float f32x4;

#define NN 4096
#define UN 256

__device__ __forceinline__ f16x8 ld_f16x8(const f16* p){ return *(const f16x8*)p; }
__device__ __forceinline__ f32x4 zero4(){ f32x4 z = {0.f,0.f,0.f,0.f}; return z; }

// Fragment-major B layout: [k/32][n/16][lane=((k>>3)&3)*16+(n&15)][j=k&7] f16.
// A wave loads fragment (kc,nt) as one coalesced 1KB read: base + lane*8.

// ---------------- K0: build wgB (f16 frag-major) + gate frag buffers ------
__global__ __launch_bounds__(256) void k0_prep(
    const float* __restrict__ wg, const float* __restrict__ wz,
    const float* __restrict__ uz, const float* __restrict__ wh,
    const float* __restrict__ uh,
    f16* __restrict__ wgB,
    f16* __restrict__ czB_h, f16* __restrict__ czB_l,
    f16* __restrict__ chB_h, f16* __restrict__ chB_l)
{
  __shared__ float lsA[32*256];
  __shared__ float lsB[32*256];
  const int t = threadIdx.x;
  const int b = blockIdx.x;
  if (b < 128){
    const int kcg = b;
    #pragma unroll 8
    for (int i = 0; i < 32; i++)
      lsA[i*256 + t] = wg[(size_t)(kcg*32 + i) * UN + t];
    __syncthreads();
    #pragma unroll
    for (int i = 0; i < 4; i++){
      int o = i*256 + t;
      int l = o & 63;
      int n = ((o >> 6) << 4) + (l & 15);
      int kl = (l >> 4) * 8;
      f16 v8[8];
      #pragma unroll
      for (int j = 0; j < 8; j++) v8[j] = (f16)lsA[(kl + j)*256 + n];
      *(uint4*)(wgB + ((size_t)kcg*1024 + o)*8) = *(const uint4*)v8;
    }
  } else {
    const int kcg = b - 128;           // 0..15, K=512
    #pragma unroll 8
    for (int i = 0; i < 32; i++){
      int kg = kcg*32 + i;
      lsA[i*256 + t] = (kg < 256) ? wz[(size_t)kg * UN + t]
                                  : uz[(size_t)(kg - 256) * UN + t];
      lsB[i*256 + t] = (kg < 256) ? wh[(size_t)kg * UN + t]
                                  : uh[(size_t)(kg - 256) * UN + t];
    }
    __syncthreads();
    #pragma unroll
    for (int i = 0; i < 4; i++){
      int o = i*256 + t;
      int l = o & 63;
      int n = ((o >> 6) << 4) + (l & 15);
      int kl = (l >> 4) * 8;
      f16 zh[8], zl[8], hh[8], hl[8];
      #pragma unroll
      for (int j = 0; j < 8; j++){
        float vz = lsA[(kl + j)*256 + n];
        float vh = lsB[(kl + j)*256 + n];
        f16 a = (f16)vz; zh[j] = a; zl[j] = (f16)(vz - (float)a);
        f16 c = (f16)vh; hh[j] = c; hl[j] = (f16)(vh - (float)c);
      }
      size_t off = ((size_t)kcg*1024 + o)*8;
      *(uint4*)(czB_h + off) = *(const uint4*)zh;
      *(uint4*)(czB_l + off) = *(const uint4*)zl;
      *(uint4*)(chB_h + off) = *(const uint4*)hh;
      *(uint4*)(chB_l + off) = *(const uint4*)hl;
    }
  }
}

// ---------------- K1: W2[node][unit] += (sum_g wa_g adj_g) @ w_gcn --------
// No LDS/barriers. Block = 4 waves x 16 rows; grid (64 m, 16 k-splits of 256).
// Software-pipelined: B half-loads + next-A prefetch overlap MFMAs.
__global__ __launch_bounds__(256) void k1_w2(
    const float* __restrict__ adj, const float* __restrict__ wa,
    const f16* __restrict__ wgB, float* __restrict__ W2)
{
  const int t = threadIdx.x, lane = t & 63, wv = t >> 6;
  const int qm = lane & 15, quad = lane >> 4;
  const int mbase = blockIdx.x * 64 + wv * 16;
  const int kbase = blockIdx.y * 256;
  const float wa0 = wa[0], wa1 = wa[1], wa2 = wa[2];
  const size_t gs = (size_t)NN * NN;
  const float* pa = adj + (size_t)(mbase + qm) * NN + kbase + quad * 8;

  f32x4 acc[16];
  #pragma unroll
  for (int i = 0; i < 16; i++) acc[i] = zero4();

  // A prefetch registers (current step)
  f32x4 g[6];
  #pragma unroll
  for (int r = 0; r < 2; r++)
    #pragma unroll
    for (int gi = 0; gi < 3; gi++)
      g[gi*2 + r] = *(const f32x4*)(pa + (size_t)gi*gs + r*4);

  for (int step = 0; step < 8; step++){
    const int kc = step * 32;
    const int kcg = (kbase + kc) >> 5;
    const f16* pb = wgB + ((size_t)kcg*1024 + lane)*8;

    // first half of B fragments
    f16x8 bf[8];
    #pragma unroll
    for (int i = 0; i < 8; i++) bf[i] = ld_f16x8(pb + i*512);

    // mix current A (VALU; overlaps in-flight B loads)
    f16x8 ah, al;
    #pragma unroll
    for (int j = 0; j < 4; j++){
      float v0 = wa0*g[0][j] + wa1*g[2][j] + wa2*g[4][j];
      float v1 = wa0*g[1][j] + wa1*g[3][j] + wa2*g[5][j];
      f16 h0 = (f16)v0, h1 = (f16)v1;
      ah[j] = h0;   al[j] = (f16)(v0 - (float)h0);
      ah[4+j] = h1; al[4+j] = (f16)(v1 - (float)h1);
    }

    // prefetch next step's A
    f32x4 gn[6];
    if (step < 7){
      const float* pan = pa + kc + 32;
      #pragma unroll
      for (int r = 0; r < 2; r++)
        #pragma unroll
        for (int gi = 0; gi < 3; gi++)
          gn[gi*2 + r] = *(const f32x4*)(pan + (size_t)gi*gs + r*4);
    }

    // second half of B fragments
    f16x8 bg[8];
    #pragma unroll
    for (int i = 0; i < 8; i++) bg[i] = ld_f16x8(pb + (8+i)*512);

    #pragma unroll
    for (int tn = 0; tn < 8; tn++){
      acc[tn] = __builtin_amdgcn_mfma_f32_16x16x32_f16(ah, bf[tn], acc[tn], 0, 0, 0);
      acc[tn] = __builtin_amdgcn_mfma_f32_16x16x32_f16(al, bf[tn], acc[tn], 0, 0, 0);
    }
    #pragma unroll
    for (int tn = 0; tn < 8; tn++){
      acc[8+tn] = __builtin_amdgcn_mfma_f32_16x16x32_f16(ah, bg[tn], acc[8+tn], 0, 0, 0);
      acc[8+tn] = __builtin_amdgcn_mfma_f32_16x16x32_f16(al, bg[tn], acc[8+tn], 0, 0, 0);
    }

    #pragma unroll
    for (int i = 0; i < 6; i++) g[i] = gn[i];
  }

  // epilogue: D[m=quad*4+r][n=tn*16+qm]; 64B-coalesced f32 atomics
  #pragma unroll
  for (int tn = 0; tn < 16; tn++)
    #pragma unroll
    for (int r = 0; r < 4; r++)
      atomicAdd(&W2[(size_t)(mbase + quad*4 + r)*UN + tn*16 + qm], acc[tn][r]);
}

// ---------------- Kcvt: W2 f32 [4096][256] -> W2B f16 frag-major ----------
__global__ __launch_bounds__(256) void k_cvt(
    const float* __restrict__ W2, f16* __restrict__ W2B)
{
  __shared__ float ls[32*256];
  const int t = threadIdx.x;
  const int kcg = blockIdx.x;            // 0..127
  #pragma unroll 8
  for (int i = 0; i < 32; i++)
    ls[i*256 + t] = W2[(size_t)(kcg*32 + i) * UN + t];
  __syncthreads();
  #pragma unroll
  for (int i = 0; i < 4; i++){
    int o = i*256 + t;
    int l = o & 63;
    int n = ((o >> 6) << 4) + (l & 15);
    int kl = (l >> 4) * 8;
    f16 v8[8];
    #pragma unroll
    for (int j = 0; j < 8; j++) v8[j] = (f16)ls[(kl + j)*256 + n];
    *(uint4*)(W2B + ((size_t)kcg*1024 + o)*8) = *(const uint4*)v8;
  }
}

// ---------------- K2: xg[m][n] += inputs @ W2 -----------------------------
__global__ __launch_bounds__(256) void k2_x(
    const float* __restrict__ inputs, const f16* __restrict__ W2B,
    float* __restrict__ xg)
{
  const int t = threadIdx.x, lane = t & 63, wv = t >> 6;
  const int qm = lane & 15, quad = lane >> 4;
  const int m0 = blockIdx.x * 16;
  const int kbase = blockIdx.y * 128;
  const float* pa = inputs + (size_t)(m0 + qm) * NN + kbase + quad * 8;

  f32x4 acc[4] = { zero4(), zero4(), zero4(), zero4() };

  #pragma unroll
  for (int kc = 0; kc < 128; kc += 32){
    f32x4 a0 = *(const f32x4*)(pa + kc);
    f32x4 a1 = *(const f32x4*)(pa + kc + 4);
    const int kcg = (kbase + kc) >> 5;
    const f16* pb = W2B + (((size_t)kcg*16 + wv*4)*64 + lane)*8;
    f16x8 bfr[4];
    #pragma unroll
    for (int tn = 0; tn < 4; tn++) bfr[tn] = ld_f16x8(pb + tn*512);
    f16x8 ah, al;
    #pragma unroll
    for (int j = 0; j < 4; j++){
      f16 h0 = (f16)a0[j], h1 = (f16)a1[j];
      ah[j] = h0;   al[j] = (f16)(a0[j] - (float)h0);
      ah[4+j] = h1; al[4+j] = (f16)(a1[j] - (float)h1);
    }
    #pragma unroll
    for (int tn = 0; tn < 4; tn++){
      acc[tn] = __builtin_amdgcn_mfma_f32_16x16x32_f16(ah, bfr[tn], acc[tn], 0, 0, 0);
      acc[tn] = __builtin_amdgcn_mfma_f32_16x16x32_f16(al, bfr[tn], acc[tn], 0, 0, 0);
    }
  }
  #pragma unroll
  for (int tn = 0; tn < 4; tn++)
    #pragma unroll
    for (int r = 0; r < 4; r++)
      atomicAdd(&xg[(size_t)(m0 + quad*4 + r)*UN + (wv*4 + tn)*16 + qm],
                acc[tn][r]);
}

// ---------------- K2b: xa = f16 hi/lo of [relu(xg) | state] ---------------
__global__ __launch_bounds__(256) void k2b_xa(
    const float* __restrict__ xg, const float* __restrict__ state,
    f16* __restrict__ xa_h, f16* __restrict__ xa_l)
{
  const size_t e = ((size_t)blockIdx.x * 256 + threadIdx.x) * 8;
  const int m = (int)(e >> 9), k0 = (int)(e & 511);
  const float* src = (k0 < 256) ? (xg + (size_t)m * UN + k0)
                                : (state + (size_t)m * UN + (k0 - 256));
  f32x4 a = *(const f32x4*)src;
  f32x4 b = *(const f32x4*)(src + 4);
  const bool rl = (k0 < 256);
  f16 hi[8], lo[8];
  #pragma unroll
  for (int j = 0; j < 4; j++){
    float va = rl ? fmaxf(a[j], 0.f) : a[j];
    float vb = rl ? fmaxf(b[j], 0.f) : b[j];
    f16 ha = (f16)va, hb = (f16)vb;
    hi[j] = ha;   lo[j] = (f16)(va - (float)ha);
    hi[4+j] = hb; lo[4+j] = (f16)(vb - (float)hb);
  }
  *(uint4*)(xa_h + e) = *(const uint4*)hi;
  *(uint4*)(xa_l + e) = *(const uint4*)lo;
}

// ---------------- K3: gate logits via MFMA, 16-way K-split ----------------
// Grid (32 m-tiles of 16, 16 k-splits of 32). Waves = n-quarters. Both gates.
__global__ __launch_bounds__(256) void k3_gates(
    const f16* __restrict__ xa_h, const f16* __restrict__ xa_l,
    const f16* __restrict__ czB_h, const f16* __restrict__ czB_l,
    const f16* __restrict__ chB_h, const f16* __restrict__ chB_l,
    float* __restrict__ lz, float* __restrict__ lh)
{
  const int t = threadIdx.x, lane = t & 63, wv = t >> 6;
  const int qm = lane & 15, quad = lane >> 4;
  const int m0 = blockIdx.x * 16;
  const int kbase = blockIdx.y * 32;
  const size_t pao = (size_t)(m0 + qm) * 512 + kbase + quad * 8;

  f32x4 az[4] = { zero4(), zero4(), zero4(), zero4() };
  f32x4 ag[4] = { zero4(), zero4(), zero4(), zero4() };

  f16x8 ah = ld_f16x8(xa_h + pao);
  f16x8 al = ld_f16x8(xa_l + pao);
  const int kcg = kbase >> 5;
  const size_t base = (((size_t)kcg*16 + wv*4)*64 + lane)*8;
  #pragma unroll
  for (int tn = 0; tn < 4; tn++){
    f16x8 bzh = ld_f16x8(czB_h + base + tn*512);
    f16x8 bzl = ld_f16x8(czB_l + base + tn*512);
    f16x8 bhh = ld_f16x8(chB_h + base + tn*512);
    f16x8 bhl = ld_f16x8(chB_l + base + tn*512);
    az[tn] = __builtin_amdgcn_mfma_f32_16x16x32_f16(ah, bzh, az[tn], 0, 0, 0);
    az[tn] = __builtin_amdgcn_mfma_f32_16x16x32_f16(al, bzh, az[tn], 0, 0, 0);
    az[tn] = __builtin_amdgcn_mfma_f32_16x16x32_f16(ah, bzl, az[tn], 0, 0, 0);
    ag[tn] = __builtin_amdgcn_mfma_f32_16x16x32_f16(ah, bhh, ag[tn], 0, 0, 0);
    ag[tn] = __builtin_amdgcn_mfma_f32_16x16x32_f16(al, bhh, ag[tn], 0, 0, 0);
    ag[tn] = __builtin_amdgcn_mfma_f32_16x16x32_f16(ah, bhl, ag[tn], 0, 0, 0);
  }
  #pragma unroll
  for (int tn = 0; tn < 4; tn++)
    #pragma unroll
    for (int r = 0; r < 4; r++){
      size_t o = (size_t)(m0 + quad*4 + r)*UN + (wv*4 + tn)*16 + qm;
      atomicAdd(&lz[o], az[tn][r]);
      atomicAdd(&lh[o], ag[tn][r]);
    }
}

// ---------------- K3b: elementwise gates + output -------------------------
__global__ __launch_bounds__(256) void k3b_out(
    const float* __restrict__ lz, const float* __restrict__ lh,
    const float* __restrict__ state,
    const float* __restrict__ bz, const float* __restrict__ bh,
    float* __restrict__ out)
{
  const size_t e = ((size_t)blockIdx.x * 256 + threadIdx.x) * 4;
  const int n = (int)(e & 255);
  f32x4 z4 = *(const f32x4*)(lz + e);
  f32x4 h4 = *(const f32x4*)(lh + e);
  f32x4 s4 = *(const f32x4*)(state + e);
  f32x4 bz4 = *(const f32x4*)(bz + n);
  f32x4 bh4 = *(const f32x4*)(bh + n);
  f32x4 o4;
  #pragma unroll
  for (int j = 0; j < 4; j++){
    float z = 1.f / (1.f + __expf(-(z4[j] + bz4[j])));
    float ex = __expf(2.f * (h4[j] + bh4[j]));
    float hh = 1.f - 2.f / (ex + 1.f);
    o4[j] = (1.f - z) * s4[j] + z * hh;
  }
  *(f32x4*)(out + e) = o4;
}

// ---------------- launch --------------------------------------------------
extern "C" void kernel_launch(void* const* d_in, const int* in_sizes, int n_in,
                              void* d_out, int out_size, void* d_ws, size_t ws_size,
                              hipStream_t stream)
{
  const float* inputs = (const float*)d_in[0];
  const float* state  = (const float*)d_in[1];
  const float* adj    = (const float*)d_in[2];
  const float* wa     = (const float*)d_in[3];
  const float* wg     = (const float*)d_in[4];
  const float* wz     = (const float*)d_in[5];
  const float* uz     = (const float*)d_in[6];
  const float* bz     = (const float*)d_in[7];
  const float* wh     = (const float*)d_in[8];
  const float* uh     = (const float*)d_in[9];
  const float* bh     = (const float*)d_in[10];
  float* out = (float*)d_out;

  char* ws = (char*)d_ws;
  float* W2    = (float*)(ws);                          // 4 MB [4096][256] f32
  float* xg    = (float*)(ws + (4u<<20));               // 512 KB [512][256]
  float* lz    = (float*)(ws + (4u<<20) + (512u<<10));  // 512 KB
  float* lh    = (float*)(ws + (5u<<20));               // 512 KB
  f16* wgB     = (f16*)(ws + (5u<<20) + (512u<<10));    // 2 MB frag-major
  f16* W2B     = (f16*)(ws + (7u<<20) + (512u<<10));    // 2 MB frag-major
  f16* xa_h    = (f16*)(ws + (9u<<20) + (512u<<10));    // 512 KB [512][512]
  f16* xa_l    = (f16*)(ws + (10u<<20));                // 512 KB
  f16* czB_h   = (f16*)(ws + (10u<<20) + (512u<<10));   // 256 KB
  f16* czB_l   = (f16*)(ws + (10u<<20) + (768u<<10));   // 256 KB
  f16* chB_h   = (f16*)(ws + (11u<<20));                // 256 KB
  f16* chB_l   = (f16*)(ws + (11u<<20) + (256u<<10));   // 256 KB

  // zero W2 + xg + lz + lh (contiguous 5.5 MB)
  hipMemsetAsync(ws, 0, (5u<<20) + (512u<<10), stream);
  k0_prep<<<144, 256, 0, stream>>>(wg, wz, uz, wh, uh,
                                   wgB, czB_h, czB_l, chB_h, chB_l);
  k1_w2<<<dim3(64, 16), 256, 0, stream>>>(adj, wa, wgB, W2);
  k_cvt<<<128, 256, 0, stream>>>(W2, W2B);
  k2_x<<<dim3(32, 32), 256, 0, stream>>>(inputs, W2B, xg);
  k2b_xa<<<128, 256, 0, stream>>>(xg, state, xa_h, xa_l);
  k3_gates<<<dim3(32, 16), 256, 0, stream>>>(xa_h, xa_l, czB_h, czB_l,
                                             chB_h, chB_l, lz, lh);
  k3b_out<<<128, 256, 0, stream>>>(lz, lh, state, bz, bh, out);
}